// Round 1
// baseline (486.003 us; speedup 1.0000x reference)
//
#include <hip/hip_runtime.h>
#include <math.h>

#define NEG_SLOPE 0.2f

// ---------------- Layer-1 node prep: h1[N,32], as1[N,2], ad1[N,2] ----------
// 32 threads per node; lane c owns channel c (head = c>>4).
__global__ void k0_prep1(const float* __restrict__ x,
                         const float* __restrict__ W1,
                         const float* __restrict__ a_src1,
                         const float* __restrict__ a_dst1,
                         float* __restrict__ h1,
                         float* __restrict__ as1,
                         float* __restrict__ ad1,
                         int N) {
    int t = blockIdx.x * blockDim.x + threadIdx.x;
    int n = t >> 5;
    int c = t & 31;
    if (n >= N) return;
    const float4 xv = reinterpret_cast<const float4*>(x)[n];  // broadcast within group
    float h = xv.x * W1[c] + xv.y * W1[32 + c] + xv.z * W1[64 + c] + xv.w * W1[96 + c];
    h1[n * 32 + c] = h;                       // coalesced 128B per group
    float ts = h * a_src1[c];                 // a_src1 flat [h*16+cc] == [c]
    float td = h * a_dst1[c];
#pragma unroll
    for (int m = 8; m >= 1; m >>= 1) {        // reduce over 16 channels of this head
        ts += __shfl_xor(ts, m);
        td += __shfl_xor(td, m);
    }
    if ((c & 15) == 0) {
        int hh = c >> 4;
        as1[n * 2 + hh] = ts;
        ad1[n * 2 + hh] = td;
    }
}

// ---------------- CSR build -------------------------------------------------
__global__ void k1a_init_deg(int* __restrict__ deg, int N) {
    int n = blockIdx.x * blockDim.x + threadIdx.x;
    if (n < N) deg[n] = 1;                    // self-loop
}

__global__ void k1b_hist(const int* __restrict__ dst, int* __restrict__ deg, int E) {
    int e = blockIdx.x * blockDim.x + threadIdx.x;
    if (e < E) atomicAdd(&deg[dst[e]], 1);
}

// single-workgroup exclusive scan (1024 threads, wave-shuffle based)
__global__ void k2_scan(const int* __restrict__ deg, int* __restrict__ rp, int N) {
    __shared__ int wsum[16];
    const int tid = threadIdx.x;
    const int lane = tid & 63, wid = tid >> 6;
    int carry = 0;
    for (int base = 0; base < N; base += 1024) {
        int i = base + tid;
        int v = (i < N) ? deg[i] : 0;
        int xx = v;
#pragma unroll
        for (int off = 1; off < 64; off <<= 1) {   // inclusive wave scan
            int t = __shfl_up(xx, off);
            if (lane >= off) xx += t;
        }
        if (lane == 63) wsum[wid] = xx;
        __syncthreads();
        int woff = 0;
        for (int w = 0; w < wid; ++w) woff += wsum[w];
        if (i < N) rp[i] = carry + woff + xx - v;  // exclusive
        int tot = 0;
        for (int w = 0; w < 16; ++w) tot += wsum[w];
        carry += tot;
        __syncthreads();
    }
    if (tid == 0) rp[N] = carry;
}

__global__ void k3a_self(const int* __restrict__ rp, int* __restrict__ fill,
                         int* __restrict__ esrt, int N) {
    int n = blockIdx.x * blockDim.x + threadIdx.x;
    if (n < N) {
        fill[n] = 1;
        esrt[rp[n]] = n;                      // self-loop in slot 0
    }
}

__global__ void k3b_scatter(const int* __restrict__ src, const int* __restrict__ dst,
                            const int* __restrict__ rp, int* __restrict__ fill,
                            int* __restrict__ esrt, int E) {
    int e = blockIdx.x * blockDim.x + threadIdx.x;
    if (e < E) {
        int d = dst[e];
        int pos = rp[d] + atomicAdd(&fill[d], 1);
        esrt[pos] = src[e];
    }
}

// ---------------- Layer-1 aggregate + fused ELU + layer-2 prep --------------
// 32 threads per node; online softmax per head; lane c owns channel c.
__global__ void k4_layer1(const int* __restrict__ rp, const int* __restrict__ esrt,
                          const float* __restrict__ h1, const float* __restrict__ as1,
                          const float* __restrict__ ad1, const float* __restrict__ b1,
                          const float* __restrict__ W2, const float* __restrict__ a_src2,
                          const float* __restrict__ a_dst2,
                          float* __restrict__ h2, float* __restrict__ as2,
                          float* __restrict__ ad2, int N) {
    int t = blockIdx.x * blockDim.x + threadIdx.x;
    int n = t >> 5;
    int c = t & 31;
    if (n >= N) return;
    int hh = c >> 4;
    float ad = ad1[n * 2 + hh];
    int p0 = rp[n], p1 = rp[n + 1];
    float m = -INFINITY, s = 0.f, acc = 0.f;
    for (int p = p0; p < p1; ++p) {
        int sn = esrt[p];                          // broadcast within group
        float e = as1[sn * 2 + hh] + ad;
        e = e > 0.f ? e : NEG_SLOPE * e;           // leaky relu
        float nm = fmaxf(m, e);
        float sc = __expf(m - nm);
        float pr = __expf(e - nm);
        s = s * sc + pr;
        acc = acc * sc + pr * h1[sn * 32 + c];     // coalesced 128B gather
        m = nm;
    }
    float o = acc / s + b1[c];
    o = o > 0.f ? o : expm1f(o);                   // ELU
    // fused layer-2 prep: h2 = o @ W2  (reduce over all 32 channels)
    float t0 = o * W2[c * 2 + 0];
    float t1 = o * W2[c * 2 + 1];
#pragma unroll
    for (int msk = 16; msk >= 1; msk >>= 1) {
        t0 += __shfl_xor(t0, msk);
        t1 += __shfl_xor(t1, msk);
    }
    if (c == 0) {
        h2[n * 2 + 0] = t0;
        h2[n * 2 + 1] = t1;
        as2[n] = t0 * a_src2[0] + t1 * a_src2[1];
        ad2[n] = t0 * a_dst2[0] + t1 * a_dst2[1];
    }
}

// ---------------- Layer-2 aggregate → output --------------------------------
__global__ void k5_layer2(const int* __restrict__ rp, const int* __restrict__ esrt,
                          const float* __restrict__ h2, const float* __restrict__ as2,
                          const float* __restrict__ ad2, const float* __restrict__ b2,
                          float* __restrict__ out, int N) {
    int n = blockIdx.x * blockDim.x + threadIdx.x;
    if (n >= N) return;
    float ad = ad2[n];
    int p0 = rp[n], p1 = rp[n + 1];
    float m = -INFINITY, s = 0.f, a0 = 0.f, a1 = 0.f;
    for (int p = p0; p < p1; ++p) {
        int sn = esrt[p];
        float e = as2[sn] + ad;
        e = e > 0.f ? e : NEG_SLOPE * e;
        float nm = fmaxf(m, e);
        float sc = __expf(m - nm);
        float pr = __expf(e - nm);
        s = s * sc + pr;
        float2 hv = reinterpret_cast<const float2*>(h2)[sn];
        a0 = a0 * sc + pr * hv.x;
        a1 = a1 * sc + pr * hv.y;
        m = nm;
    }
    out[n * 2 + 0] = a0 / s + b2[0];
    out[n * 2 + 1] = a1 / s + b2[1];
}

extern "C" void kernel_launch(void* const* d_in, const int* in_sizes, int n_in,
                              void* d_out, int out_size, void* d_ws, size_t ws_size,
                              hipStream_t stream) {
    const float* x      = (const float*)d_in[0];
    const int*   ei     = (const int*)d_in[1];   // int32 (JAX x64 disabled)
    const float* W1     = (const float*)d_in[2];
    const float* a_src1 = (const float*)d_in[3];
    const float* a_dst1 = (const float*)d_in[4];
    const float* b1     = (const float*)d_in[5];
    const float* W2     = (const float*)d_in[6];
    const float* a_src2 = (const float*)d_in[7];
    const float* a_dst2 = (const float*)d_in[8];
    const float* b2     = (const float*)d_in[9];
    float* out = (float*)d_out;

    const int N = in_sizes[0] / 4;    // x is [N,4]
    const int E = in_sizes[1] / 2;    // edge_index is [2,E]
    const int* srcp = ei;
    const int* dstp = ei + E;

    // workspace layout (all 4B elems, sizes kept even for float2/float4 align)
    float* h1  = (float*)d_ws;          // N*32
    float* as1 = h1  + (size_t)N * 32;  // N*2
    float* ad1 = as1 + (size_t)N * 2;   // N*2
    float* h2  = ad1 + (size_t)N * 2;   // N*2
    float* as2 = h2  + (size_t)N * 2;   // N
    float* ad2 = as2 + (size_t)N;       // N
    int* deg  = (int*)(ad2 + (size_t)N);   // N
    int* rp   = deg  + (size_t)N;          // N+1 (rounded)
    int* fill = rp   + (size_t)(N + 4);    // N
    int* esrt = fill + (size_t)N;          // E+N

    const int BT = 256;
    k0_prep1<<<((size_t)N * 32 + BT - 1) / BT, BT, 0, stream>>>(
        x, W1, a_src1, a_dst1, h1, as1, ad1, N);
    k1a_init_deg<<<(N + BT - 1) / BT, BT, 0, stream>>>(deg, N);
    k1b_hist<<<(E + BT - 1) / BT, BT, 0, stream>>>(dstp, deg, E);
    k2_scan<<<1, 1024, 0, stream>>>(deg, rp, N);
    k3a_self<<<(N + BT - 1) / BT, BT, 0, stream>>>(rp, fill, esrt, N);
    k3b_scatter<<<(E + BT - 1) / BT, BT, 0, stream>>>(srcp, dstp, rp, fill, esrt, E);
    k4_layer1<<<((size_t)N * 32 + BT - 1) / BT, BT, 0, stream>>>(
        rp, esrt, h1, as1, ad1, b1, W2, a_src2, a_dst2, h2, as2, ad2, N);
    k5_layer2<<<(N + BT - 1) / BT, BT, 0, stream>>>(rp, esrt, h2, as2, ad2, b2, out, N);
}

// Round 2
// 389.504 us; speedup vs baseline: 1.2477x; 1.2477x over previous
//
#include <hip/hip_runtime.h>
#include <math.h>

#define NEG_SLOPE 0.2f
#define SCAN_CHUNK 2048   // per-block elements in hierarchical scan (256 thr * 8)

// ---------------- Layer-1 node prep: h1[N,32], as1[N,2], ad1[N,2] ----------
// 32 threads per node; lane c owns channel c (head = c>>4).
__global__ void k0_prep1(const float* __restrict__ x,
                         const float* __restrict__ W1,
                         const float* __restrict__ a_src1,
                         const float* __restrict__ a_dst1,
                         float* __restrict__ h1,
                         float* __restrict__ as1,
                         float* __restrict__ ad1,
                         int N) {
    int t = blockIdx.x * blockDim.x + threadIdx.x;
    int n = t >> 5;
    int c = t & 31;
    if (n >= N) return;
    const float4 xv = reinterpret_cast<const float4*>(x)[n];  // broadcast within group
    float h = xv.x * W1[c] + xv.y * W1[32 + c] + xv.z * W1[64 + c] + xv.w * W1[96 + c];
    h1[n * 32 + c] = h;                       // coalesced 128B per group
    float ts = h * a_src1[c];                 // a_src1 flat [h*16+cc] == [c]
    float td = h * a_dst1[c];
#pragma unroll
    for (int m = 8; m >= 1; m >>= 1) {        // reduce over 16 channels of this head
        ts += __shfl_xor(ts, m);
        td += __shfl_xor(td, m);
    }
    if ((c & 15) == 0) {
        int hh = c >> 4;
        as1[n * 2 + hh] = ts;
        ad1[n * 2 + hh] = td;
    }
}

// ---------------- CSR build -------------------------------------------------
__global__ void k1a_init_deg(int* __restrict__ deg, int N) {
    int n = blockIdx.x * blockDim.x + threadIdx.x;
    if (n < N) deg[n] = 1;                    // self-loop
}

__global__ void k1b_hist(const int* __restrict__ dst, int* __restrict__ deg, int E) {
    int e = blockIdx.x * blockDim.x + threadIdx.x;
    if (e < E) atomicAdd(&deg[dst[e]], 1);
}

// --------- hierarchical exclusive scan: partials -> scan partials -> rescan -
// K2a: per-block sum of SCAN_CHUNK elems
__global__ void k2a_partials(const int* __restrict__ deg, int* __restrict__ bsum, int N) {
    __shared__ int ws[4];
    const int tid = threadIdx.x;              // 256
    const int lane = tid & 63, wid = tid >> 6;
    int base = blockIdx.x * SCAN_CHUNK + tid * 8;
    int lsum = 0;
#pragma unroll
    for (int i = 0; i < 8; ++i) {
        int idx = base + i;
        lsum += (idx < N) ? deg[idx] : 0;
    }
#pragma unroll
    for (int m = 32; m >= 1; m >>= 1) lsum += __shfl_xor(lsum, m);
    if (lane == 0) ws[wid] = lsum;
    __syncthreads();
    if (tid == 0) bsum[blockIdx.x] = ws[0] + ws[1] + ws[2] + ws[3];
}

// K2b: exclusive scan of the (small) block-sum array; also writes rp[N]=total
__global__ void k2b_scanb(const int* __restrict__ bsum, int* __restrict__ bscan,
                          int nb, int* __restrict__ rp, int N) {
    __shared__ int wsum[16];
    const int tid = threadIdx.x;              // 1024
    const int lane = tid & 63, wid = tid >> 6;
    int carry = 0;
    for (int base = 0; base < nb; base += 1024) {
        int i = base + tid;
        int v = (i < nb) ? bsum[i] : 0;
        int xx = v;
#pragma unroll
        for (int off = 1; off < 64; off <<= 1) {
            int t = __shfl_up(xx, off);
            if (lane >= off) xx += t;
        }
        if (lane == 63) wsum[wid] = xx;
        __syncthreads();
        int woff = 0;
        for (int w = 0; w < wid; ++w) woff += wsum[w];
        if (i < nb) bscan[i] = carry + woff + xx - v;
        int tot = 0;
        for (int w = 0; w < 16; ++w) tot += wsum[w];
        carry += tot;
        __syncthreads();
    }
    if (tid == 0) rp[N] = carry;
}

// K2c: per-block exclusive scan + block offset -> rp[0..N-1]
__global__ void k2c_scan(const int* __restrict__ deg, const int* __restrict__ bscan,
                         int* __restrict__ rp, int N) {
    __shared__ int ws[4];
    const int tid = threadIdx.x;              // 256
    const int lane = tid & 63, wid = tid >> 6;
    int base = blockIdx.x * SCAN_CHUNK + tid * 8;
    int v[8], pre[8];
    int lsum = 0;
#pragma unroll
    for (int i = 0; i < 8; ++i) {
        int idx = base + i;
        v[i] = (idx < N) ? deg[idx] : 0;
        pre[i] = lsum;                        // thread-local exclusive prefix
        lsum += v[i];
    }
    int xs = lsum;
#pragma unroll
    for (int off = 1; off < 64; off <<= 1) {  // inclusive wave scan of thread sums
        int t = __shfl_up(xs, off);
        if (lane >= off) xs += t;
    }
    if (lane == 63) ws[wid] = xs;
    __syncthreads();
    int woff = 0;
    for (int w = 0; w < wid; ++w) woff += ws[w];
    int off0 = bscan[blockIdx.x] + woff + xs - lsum;  // thread's exclusive base
#pragma unroll
    for (int i = 0; i < 8; ++i) {
        int idx = base + i;
        if (idx < N) rp[idx] = off0 + pre[i];
    }
}

__global__ void k3a_self(const int* __restrict__ rp, int* __restrict__ fill,
                         int* __restrict__ esrt, int N) {
    int n = blockIdx.x * blockDim.x + threadIdx.x;
    if (n < N) {
        fill[n] = 1;
        esrt[rp[n]] = n;                      // self-loop in slot 0
    }
}

__global__ void k3b_scatter(const int* __restrict__ src, const int* __restrict__ dst,
                            const int* __restrict__ rp, int* __restrict__ fill,
                            int* __restrict__ esrt, int E) {
    int e = blockIdx.x * blockDim.x + threadIdx.x;
    if (e < E) {
        int d = dst[e];
        int pos = rp[d] + atomicAdd(&fill[d], 1);
        esrt[pos] = src[e];
    }
}

// ---------------- Layer-1 aggregate + fused ELU + layer-2 prep --------------
// 32 threads per node; online softmax per head; lane c owns channel c.
__global__ void k4_layer1(const int* __restrict__ rp, const int* __restrict__ esrt,
                          const float* __restrict__ h1, const float* __restrict__ as1,
                          const float* __restrict__ ad1, const float* __restrict__ b1,
                          const float* __restrict__ W2, const float* __restrict__ a_src2,
                          const float* __restrict__ a_dst2,
                          float* __restrict__ h2, float* __restrict__ as2,
                          float* __restrict__ ad2, int N) {
    int t = blockIdx.x * blockDim.x + threadIdx.x;
    int n = t >> 5;
    int c = t & 31;
    if (n >= N) return;
    int hh = c >> 4;
    float ad = ad1[n * 2 + hh];
    int p0 = rp[n], p1 = rp[n + 1];
    float m = -INFINITY, s = 0.f, acc = 0.f;
    for (int p = p0; p < p1; ++p) {
        int sn = esrt[p];                          // broadcast within group
        float e = as1[sn * 2 + hh] + ad;
        e = e > 0.f ? e : NEG_SLOPE * e;           // leaky relu
        float nm = fmaxf(m, e);
        float sc = __expf(m - nm);
        float pr = __expf(e - nm);
        s = s * sc + pr;
        acc = acc * sc + pr * h1[sn * 32 + c];     // coalesced 128B gather
        m = nm;
    }
    float o = acc / s + b1[c];
    o = o > 0.f ? o : expm1f(o);                   // ELU
    // fused layer-2 prep: h2 = o @ W2  (reduce over all 32 channels)
    float t0 = o * W2[c * 2 + 0];
    float t1 = o * W2[c * 2 + 1];
#pragma unroll
    for (int msk = 16; msk >= 1; msk >>= 1) {
        t0 += __shfl_xor(t0, msk);
        t1 += __shfl_xor(t1, msk);
    }
    if (c == 0) {
        h2[n * 2 + 0] = t0;
        h2[n * 2 + 1] = t1;
        as2[n] = t0 * a_src2[0] + t1 * a_src2[1];
        ad2[n] = t0 * a_dst2[0] + t1 * a_dst2[1];
    }
}

// ---------------- Layer-2 aggregate → output --------------------------------
__global__ void k5_layer2(const int* __restrict__ rp, const int* __restrict__ esrt,
                          const float* __restrict__ h2, const float* __restrict__ as2,
                          const float* __restrict__ ad2, const float* __restrict__ b2,
                          float* __restrict__ out, int N) {
    int n = blockIdx.x * blockDim.x + threadIdx.x;
    if (n >= N) return;
    float ad = ad2[n];
    int p0 = rp[n], p1 = rp[n + 1];
    float m = -INFINITY, s = 0.f, a0 = 0.f, a1 = 0.f;
    for (int p = p0; p < p1; ++p) {
        int sn = esrt[p];
        float e = as2[sn] + ad;
        e = e > 0.f ? e : NEG_SLOPE * e;
        float nm = fmaxf(m, e);
        float sc = __expf(m - nm);
        float pr = __expf(e - nm);
        s = s * sc + pr;
        float2 hv = reinterpret_cast<const float2*>(h2)[sn];
        a0 = a0 * sc + pr * hv.x;
        a1 = a1 * sc + pr * hv.y;
        m = nm;
    }
    out[n * 2 + 0] = a0 / s + b2[0];
    out[n * 2 + 1] = a1 / s + b2[1];
}

extern "C" void kernel_launch(void* const* d_in, const int* in_sizes, int n_in,
                              void* d_out, int out_size, void* d_ws, size_t ws_size,
                              hipStream_t stream) {
    const float* x      = (const float*)d_in[0];
    const int*   ei     = (const int*)d_in[1];   // int32 (JAX x64 disabled)
    const float* W1     = (const float*)d_in[2];
    const float* a_src1 = (const float*)d_in[3];
    const float* a_dst1 = (const float*)d_in[4];
    const float* b1     = (const float*)d_in[5];
    const float* W2     = (const float*)d_in[6];
    const float* a_src2 = (const float*)d_in[7];
    const float* a_dst2 = (const float*)d_in[8];
    const float* b2     = (const float*)d_in[9];
    float* out = (float*)d_out;

    const int N = in_sizes[0] / 4;    // x is [N,4]
    const int E = in_sizes[1] / 2;    // edge_index is [2,E]
    const int* srcp = ei;
    const int* dstp = ei + E;
    const int nb = (N + SCAN_CHUNK - 1) / SCAN_CHUNK;

    // workspace layout (all 4B elems)
    float* h1   = (float*)d_ws;          // N*32
    float* as1  = h1  + (size_t)N * 32;  // N*2
    float* ad1  = as1 + (size_t)N * 2;   // N*2
    float* h2   = ad1 + (size_t)N * 2;   // N*2
    float* as2  = h2  + (size_t)N * 2;   // N
    float* ad2  = as2 + (size_t)N;       // N
    int* deg   = (int*)(ad2 + (size_t)N);   // N
    int* rp    = deg  + (size_t)N;          // N+1 (rounded to +4)
    int* fill  = rp   + (size_t)(N + 4);    // N
    int* bsum  = fill + (size_t)N;          // nb
    int* bscan = bsum + (size_t)nb;         // nb
    int* esrt  = bscan + (size_t)nb;        // E+N

    const int BT = 256;
    k0_prep1<<<((size_t)N * 32 + BT - 1) / BT, BT, 0, stream>>>(
        x, W1, a_src1, a_dst1, h1, as1, ad1, N);
    k1a_init_deg<<<(N + BT - 1) / BT, BT, 0, stream>>>(deg, N);
    k1b_hist<<<(E + BT - 1) / BT, BT, 0, stream>>>(dstp, deg, E);
    k2a_partials<<<nb, 256, 0, stream>>>(deg, bsum, N);
    k2b_scanb<<<1, 1024, 0, stream>>>(bsum, bscan, nb, rp, N);
    k2c_scan<<<nb, 256, 0, stream>>>(deg, bscan, rp, N);
    k3a_self<<<(N + BT - 1) / BT, BT, 0, stream>>>(rp, fill, esrt, N);
    k3b_scatter<<<(E + BT - 1) / BT, BT, 0, stream>>>(srcp, dstp, rp, fill, esrt, E);
    k4_layer1<<<((size_t)N * 32 + BT - 1) / BT, BT, 0, stream>>>(
        rp, esrt, h1, as1, ad1, b1, W2, a_src2, a_dst2, h2, as2, ad2, N);
    k5_layer2<<<(N + BT - 1) / BT, BT, 0, stream>>>(rp, esrt, h2, as2, ad2, b2, out, N);
}

// Round 3
// 280.946 us; speedup vs baseline: 1.7299x; 1.3864x over previous
//
#include <hip/hip_runtime.h>
#include <hip/hip_fp16.h>
#include <math.h>

#define NEG_SLOPE 0.2f
#define SCAN_CHUNK 2048   // per-block elements in hierarchical scan (256 thr * 8)
#define ECLAMP 80.0f      // exp() inf-safety clamp (never hit statistically)

// ---------------- Layer-1 node prep: h1[N,32] (fp16), as1[N,2], ad1[N,2] ----
// 32 threads per node; lane c owns channel c (head = c>>4).
__global__ void k0_prep1(const float* __restrict__ x,
                         const float* __restrict__ W1,
                         const float* __restrict__ a_src1,
                         const float* __restrict__ a_dst1,
                         __half* __restrict__ h1,
                         float* __restrict__ as1,
                         float* __restrict__ ad1,
                         int N) {
    int t = blockIdx.x * blockDim.x + threadIdx.x;
    int n = t >> 5;
    int c = t & 31;
    if (n >= N) return;
    const float4 xv = reinterpret_cast<const float4*>(x)[n];  // broadcast within group
    float h = xv.x * W1[c] + xv.y * W1[32 + c] + xv.z * W1[64 + c] + xv.w * W1[96 + c];
    h1[n * 32 + c] = __float2half(h);         // coalesced 64B per group
    float ts = h * a_src1[c];                 // a_src1 flat [h*16+cc] == [c]
    float td = h * a_dst1[c];
#pragma unroll
    for (int m = 8; m >= 1; m >>= 1) {        // reduce over 16 channels of this head
        ts += __shfl_xor(ts, m);
        td += __shfl_xor(td, m);
    }
    if ((c & 15) == 0) {
        int hh = c >> 4;
        as1[n * 2 + hh] = ts;
        ad1[n * 2 + hh] = td;
    }
}

// ---------------- CSR build -------------------------------------------------
__global__ void k1a_init_deg(int* __restrict__ deg, int N) {
    int n = blockIdx.x * blockDim.x + threadIdx.x;
    if (n < N) deg[n] = 1;                    // self-loop occupies slot 0
}

// histogram + per-edge rank (rank starts at 1; slot 0 is the self-loop)
__global__ void k1b_hist(const int* __restrict__ dst, int* __restrict__ deg,
                         int* __restrict__ rank, int E) {
    int e = blockIdx.x * blockDim.x + threadIdx.x;
    if (e < E) rank[e] = atomicAdd(&deg[dst[e]], 1);
}

// --------- hierarchical exclusive scan: partials -> scan partials -> rescan -
__global__ void k2a_partials(const int* __restrict__ deg, int* __restrict__ bsum, int N) {
    __shared__ int ws[4];
    const int tid = threadIdx.x;              // 256
    const int lane = tid & 63, wid = tid >> 6;
    int base = blockIdx.x * SCAN_CHUNK + tid * 8;
    int lsum = 0;
#pragma unroll
    for (int i = 0; i < 8; ++i) {
        int idx = base + i;
        lsum += (idx < N) ? deg[idx] : 0;
    }
#pragma unroll
    for (int m = 32; m >= 1; m >>= 1) lsum += __shfl_xor(lsum, m);
    if (lane == 0) ws[wid] = lsum;
    __syncthreads();
    if (tid == 0) bsum[blockIdx.x] = ws[0] + ws[1] + ws[2] + ws[3];
}

__global__ void k2b_scanb(const int* __restrict__ bsum, int* __restrict__ bscan,
                          int nb, int* __restrict__ rp, int N) {
    __shared__ int wsum[16];
    const int tid = threadIdx.x;              // 1024
    const int lane = tid & 63, wid = tid >> 6;
    int carry = 0;
    for (int base = 0; base < nb; base += 1024) {
        int i = base + tid;
        int v = (i < nb) ? bsum[i] : 0;
        int xx = v;
#pragma unroll
        for (int off = 1; off < 64; off <<= 1) {
            int t = __shfl_up(xx, off);
            if (lane >= off) xx += t;
        }
        if (lane == 63) wsum[wid] = xx;
        __syncthreads();
        int woff = 0;
        for (int w = 0; w < wid; ++w) woff += wsum[w];
        if (i < nb) bscan[i] = carry + woff + xx - v;
        int tot = 0;
        for (int w = 0; w < 16; ++w) tot += wsum[w];
        carry += tot;
        __syncthreads();
    }
    if (tid == 0) rp[N] = carry;
}

__global__ void k2c_scan(const int* __restrict__ deg, const int* __restrict__ bscan,
                         int* __restrict__ rp, int N) {
    __shared__ int ws[4];
    const int tid = threadIdx.x;              // 256
    const int lane = tid & 63, wid = tid >> 6;
    int base = blockIdx.x * SCAN_CHUNK + tid * 8;
    int v[8], pre[8];
    int lsum = 0;
#pragma unroll
    for (int i = 0; i < 8; ++i) {
        int idx = base + i;
        v[i] = (idx < N) ? deg[idx] : 0;
        pre[i] = lsum;
        lsum += v[i];
    }
    int xs = lsum;
#pragma unroll
    for (int off = 1; off < 64; off <<= 1) {
        int t = __shfl_up(xs, off);
        if (lane >= off) xs += t;
    }
    if (lane == 63) ws[wid] = xs;
    __syncthreads();
    int woff = 0;
    for (int w = 0; w < wid; ++w) woff += ws[w];
    int off0 = bscan[blockIdx.x] + woff + xs - lsum;
#pragma unroll
    for (int i = 0; i < 8; ++i) {
        int idx = base + i;
        if (idx < N) rp[idx] = off0 + pre[i];
    }
}

__global__ void k3a_self(const int* __restrict__ rp, int* __restrict__ esrt, int N) {
    int n = blockIdx.x * blockDim.x + threadIdx.x;
    if (n < N) esrt[rp[n]] = n;               // self-loop in slot 0
}

// atomic-free scatter: position known from precomputed rank
__global__ void k3b_scatter(const int* __restrict__ src, const int* __restrict__ dst,
                            const int* __restrict__ rp, const int* __restrict__ rank,
                            int* __restrict__ esrt, int E) {
    int e = blockIdx.x * blockDim.x + threadIdx.x;
    if (e < E) {
        int pos = rp[dst[e]] + rank[e];
        esrt[pos] = src[e];
    }
}

// ---------------- Layer-1 aggregate + fused ELU + layer-2 prep --------------
// 32 threads per node; plain (no-max) softmax; lane c owns channel c.
__global__ void k4_layer1(const int* __restrict__ rp, const int* __restrict__ esrt,
                          const __half* __restrict__ h1, const float* __restrict__ as1,
                          const float* __restrict__ ad1, const float* __restrict__ b1,
                          const float* __restrict__ W2, const float* __restrict__ a_src2,
                          const float* __restrict__ a_dst2,
                          float* __restrict__ h2, float* __restrict__ as2,
                          float* __restrict__ ad2, int N) {
    int t = blockIdx.x * blockDim.x + threadIdx.x;
    int n = t >> 5;
    int c = t & 31;
    if (n >= N) return;
    int hh = c >> 4;
    float ad = ad1[n * 2 + hh];
    const float2* as1v = reinterpret_cast<const float2*>(as1);
    int p0 = rp[n], p1 = rp[n + 1];
    float s0 = 0.f, s1 = 0.f, acc0 = 0.f, acc1 = 0.f;
    int p = p0;
    for (; p + 1 < p1; p += 2) {              // 2 independent chains for MLP
        int sa = esrt[p];
        int sb = esrt[p + 1];
        float2 va = as1v[sa];
        float2 vb = as1v[sb];
        float ha = __half2float(h1[sa * 32 + c]);
        float hb = __half2float(h1[sb * 32 + c]);
        float ea = (hh ? va.y : va.x) + ad;
        float eb = (hh ? vb.y : vb.x) + ad;
        ea = ea > 0.f ? ea : NEG_SLOPE * ea;
        eb = eb > 0.f ? eb : NEG_SLOPE * eb;
        float pa = __expf(fminf(ea, ECLAMP));
        float pb = __expf(fminf(eb, ECLAMP));
        s0 += pa;   acc0 += pa * ha;
        s1 += pb;   acc1 += pb * hb;
    }
    if (p < p1) {
        int sa = esrt[p];
        float2 va = as1v[sa];
        float ha = __half2float(h1[sa * 32 + c]);
        float ea = (hh ? va.y : va.x) + ad;
        ea = ea > 0.f ? ea : NEG_SLOPE * ea;
        float pa = __expf(fminf(ea, ECLAMP));
        s0 += pa;   acc0 += pa * ha;
    }
    float s = s0 + s1;
    float acc = acc0 + acc1;
    float o = acc / s + b1[c];
    o = o > 0.f ? o : expm1f(o);                   // ELU
    // fused layer-2 prep: h2 = o @ W2  (reduce over all 32 channels)
    float t0 = o * W2[c * 2 + 0];
    float t1 = o * W2[c * 2 + 1];
#pragma unroll
    for (int msk = 16; msk >= 1; msk >>= 1) {
        t0 += __shfl_xor(t0, msk);
        t1 += __shfl_xor(t1, msk);
    }
    if (c == 0) {
        h2[n * 2 + 0] = t0;
        h2[n * 2 + 1] = t1;
        as2[n] = t0 * a_src2[0] + t1 * a_src2[1];
        ad2[n] = t0 * a_dst2[0] + t1 * a_dst2[1];
    }
}

// ---------------- Layer-2 aggregate → output --------------------------------
__global__ void k5_layer2(const int* __restrict__ rp, const int* __restrict__ esrt,
                          const float* __restrict__ h2, const float* __restrict__ as2,
                          const float* __restrict__ ad2, const float* __restrict__ b2,
                          float* __restrict__ out, int N) {
    int n = blockIdx.x * blockDim.x + threadIdx.x;
    if (n >= N) return;
    float ad = ad2[n];
    int p0 = rp[n], p1 = rp[n + 1];
    float s0 = 0.f, s1 = 0.f, x0 = 0.f, x1 = 0.f, y0 = 0.f, y1 = 0.f;
    int p = p0;
    for (; p + 1 < p1; p += 2) {
        int sa = esrt[p];
        int sb = esrt[p + 1];
        float ea = as2[sa] + ad;
        float eb = as2[sb] + ad;
        float2 hva = reinterpret_cast<const float2*>(h2)[sa];
        float2 hvb = reinterpret_cast<const float2*>(h2)[sb];
        ea = ea > 0.f ? ea : NEG_SLOPE * ea;
        eb = eb > 0.f ? eb : NEG_SLOPE * eb;
        float pa = __expf(fminf(ea, ECLAMP));
        float pb = __expf(fminf(eb, ECLAMP));
        s0 += pa;  x0 += pa * hva.x;  y0 += pa * hva.y;
        s1 += pb;  x1 += pb * hvb.x;  y1 += pb * hvb.y;
    }
    if (p < p1) {
        int sa = esrt[p];
        float ea = as2[sa] + ad;
        float2 hva = reinterpret_cast<const float2*>(h2)[sa];
        ea = ea > 0.f ? ea : NEG_SLOPE * ea;
        float pa = __expf(fminf(ea, ECLAMP));
        s0 += pa;  x0 += pa * hva.x;  y0 += pa * hva.y;
    }
    float s = s0 + s1;
    out[n * 2 + 0] = (x0 + x1) / s + b2[0];
    out[n * 2 + 1] = (y0 + y1) / s + b2[1];
}

extern "C" void kernel_launch(void* const* d_in, const int* in_sizes, int n_in,
                              void* d_out, int out_size, void* d_ws, size_t ws_size,
                              hipStream_t stream) {
    const float* x      = (const float*)d_in[0];
    const int*   ei     = (const int*)d_in[1];   // int32 (JAX x64 disabled)
    const float* W1     = (const float*)d_in[2];
    const float* a_src1 = (const float*)d_in[3];
    const float* a_dst1 = (const float*)d_in[4];
    const float* b1     = (const float*)d_in[5];
    const float* W2     = (const float*)d_in[6];
    const float* a_src2 = (const float*)d_in[7];
    const float* a_dst2 = (const float*)d_in[8];
    const float* b2     = (const float*)d_in[9];
    float* out = (float*)d_out;

    const int N = in_sizes[0] / 4;    // x is [N,4]
    const int E = in_sizes[1] / 2;    // edge_index is [2,E]
    const int* srcp = ei;
    const int* dstp = ei + E;
    const int nb = (N + SCAN_CHUNK - 1) / SCAN_CHUNK;

    // workspace layout
    __half* h1  = (__half*)d_ws;                 // N*32 fp16
    float* as1  = (float*)(h1 + (size_t)N * 32); // N*2
    float* ad1  = as1 + (size_t)N * 2;           // N*2
    float* h2   = ad1 + (size_t)N * 2;           // N*2
    float* as2  = h2  + (size_t)N * 2;           // N
    float* ad2  = as2 + (size_t)N;               // N
    int* deg   = (int*)(ad2 + (size_t)N);        // N
    int* rp    = deg  + (size_t)N;               // N+1 (rounded to +4)
    int* rank  = rp   + (size_t)(N + 4);         // E
    int* bsum  = rank + (size_t)E;               // nb
    int* bscan = bsum + (size_t)nb;              // nb
    int* esrt  = bscan + (size_t)nb;             // E+N

    const int BT = 256;
    k0_prep1<<<((size_t)N * 32 + BT - 1) / BT, BT, 0, stream>>>(
        x, W1, a_src1, a_dst1, h1, as1, ad1, N);
    k1a_init_deg<<<(N + BT - 1) / BT, BT, 0, stream>>>(deg, N);
    k1b_hist<<<(E + BT - 1) / BT, BT, 0, stream>>>(dstp, deg, rank, E);
    k2a_partials<<<nb, 256, 0, stream>>>(deg, bsum, N);
    k2b_scanb<<<1, 1024, 0, stream>>>(bsum, bscan, nb, rp, N);
    k2c_scan<<<nb, 256, 0, stream>>>(deg, bscan, rp, N);
    k3a_self<<<(N + BT - 1) / BT, BT, 0, stream>>>(rp, esrt, N);
    k3b_scatter<<<(E + BT - 1) / BT, BT, 0, stream>>>(srcp, dstp, rp, rank, esrt, E);
    k4_layer1<<<((size_t)N * 32 + BT - 1) / BT, BT, 0, stream>>>(
        rp, esrt, h1, as1, ad1, b1, W2, a_src2, a_dst2, h2, as2, ad2, N);
    k5_layer2<<<(N + BT - 1) / BT, BT, 0, stream>>>(rp, esrt, h2, as2, ad2, b2, out, N);
}

// Round 4
// 259.196 us; speedup vs baseline: 1.8750x; 1.0839x over previous
//
#include <hip/hip_runtime.h>
#include <hip/hip_fp16.h>
#include <math.h>

#define NEG_SLOPE 0.2f
#define SCAN_CHUNK 2048   // per-block elements in hierarchical scan (256 thr * 8)
#define ECLAMP 80.0f      // exp() inf-safety clamp (never hit statistically)

__device__ __forceinline__ float lrelu(float e) {
    return e > 0.f ? e : NEG_SLOPE * e;
}

// ---------------- Layer-1 node prep: h1[N,32] (fp16), as1[N,2], ad1[N,2] ----
// 32 threads per node; lane c owns channel c (head = c>>4).
__global__ void k0_prep1(const float* __restrict__ x,
                         const float* __restrict__ W1,
                         const float* __restrict__ a_src1,
                         const float* __restrict__ a_dst1,
                         __half* __restrict__ h1,
                         float* __restrict__ as1,
                         float* __restrict__ ad1,
                         int N) {
    int t = blockIdx.x * blockDim.x + threadIdx.x;
    int n = t >> 5;
    int c = t & 31;
    if (n >= N) return;
    const float4 xv = reinterpret_cast<const float4*>(x)[n];  // broadcast within group
    float h = xv.x * W1[c] + xv.y * W1[32 + c] + xv.z * W1[64 + c] + xv.w * W1[96 + c];
    h1[n * 32 + c] = __float2half(h);         // coalesced 64B per group
    float ts = h * a_src1[c];                 // a_src1 flat [h*16+cc] == [c]
    float td = h * a_dst1[c];
#pragma unroll
    for (int m = 8; m >= 1; m >>= 1) {        // reduce over 16 channels of this head
        ts += __shfl_xor(ts, m);
        td += __shfl_xor(td, m);
    }
    if ((c & 15) == 0) {
        int hh = c >> 4;
        as1[n * 2 + hh] = ts;
        ad1[n * 2 + hh] = td;
    }
}

// ---------------- CSR build -------------------------------------------------
__global__ void k1a_init_deg(int* __restrict__ deg, int N) {
    int n = blockIdx.x * blockDim.x + threadIdx.x;
    if (n < N) deg[n] = 0;                    // self-loop handled inline later
}

// histogram + per-edge rank (0-based)
__global__ void k1b_hist(const int* __restrict__ dst, int* __restrict__ deg,
                         int* __restrict__ rank, int E) {
    int e = blockIdx.x * blockDim.x + threadIdx.x;
    if (e < E) rank[e] = atomicAdd(&deg[dst[e]], 1);
}

// --------- hierarchical exclusive scan: partials -> scan partials -> rescan -
__global__ void k2a_partials(const int* __restrict__ deg, int* __restrict__ bsum, int N) {
    __shared__ int ws[4];
    const int tid = threadIdx.x;              // 256
    const int lane = tid & 63, wid = tid >> 6;
    int base = blockIdx.x * SCAN_CHUNK + tid * 8;
    int lsum = 0;
#pragma unroll
    for (int i = 0; i < 8; ++i) {
        int idx = base + i;
        lsum += (idx < N) ? deg[idx] : 0;
    }
#pragma unroll
    for (int m = 32; m >= 1; m >>= 1) lsum += __shfl_xor(lsum, m);
    if (lane == 0) ws[wid] = lsum;
    __syncthreads();
    if (tid == 0) bsum[blockIdx.x] = ws[0] + ws[1] + ws[2] + ws[3];
}

__global__ void k2b_scanb(const int* __restrict__ bsum, int* __restrict__ bscan,
                          int nb, int* __restrict__ rp, int N) {
    __shared__ int wsum[16];
    const int tid = threadIdx.x;              // 1024
    const int lane = tid & 63, wid = tid >> 6;
    int carry = 0;
    for (int base = 0; base < nb; base += 1024) {
        int i = base + tid;
        int v = (i < nb) ? bsum[i] : 0;
        int xx = v;
#pragma unroll
        for (int off = 1; off < 64; off <<= 1) {
            int t = __shfl_up(xx, off);
            if (lane >= off) xx += t;
        }
        if (lane == 63) wsum[wid] = xx;
        __syncthreads();
        int woff = 0;
        for (int w = 0; w < wid; ++w) woff += wsum[w];
        if (i < nb) bscan[i] = carry + woff + xx - v;
        int tot = 0;
        for (int w = 0; w < 16; ++w) tot += wsum[w];
        carry += tot;
        __syncthreads();
    }
    if (tid == 0) rp[N] = carry;
}

__global__ void k2c_scan(const int* __restrict__ deg, const int* __restrict__ bscan,
                         int* __restrict__ rp, int N) {
    __shared__ int ws[4];
    const int tid = threadIdx.x;              // 256
    const int lane = tid & 63, wid = tid >> 6;
    int base = blockIdx.x * SCAN_CHUNK + tid * 8;
    int v[8], pre[8];
    int lsum = 0;
#pragma unroll
    for (int i = 0; i < 8; ++i) {
        int idx = base + i;
        v[i] = (idx < N) ? deg[idx] : 0;
        pre[i] = lsum;
        lsum += v[i];
    }
    int xs = lsum;
#pragma unroll
    for (int off = 1; off < 64; off <<= 1) {
        int t = __shfl_up(xs, off);
        if (lane >= off) xs += t;
    }
    if (lane == 63) ws[wid] = xs;
    __syncthreads();
    int woff = 0;
    for (int w = 0; w < wid; ++w) woff += ws[w];
    int off0 = bscan[blockIdx.x] + woff + xs - lsum;
#pragma unroll
    for (int i = 0; i < 8; ++i) {
        int idx = base + i;
        if (idx < N) rp[idx] = off0 + pre[i];
    }
}

// atomic-free scatter: position known from precomputed rank
__global__ void k3b_scatter(const int* __restrict__ src, const int* __restrict__ dst,
                            const int* __restrict__ rp, const int* __restrict__ rank,
                            int* __restrict__ esrt, int E) {
    int e = blockIdx.x * blockDim.x + threadIdx.x;
    if (e < E) {
        int pos = rp[dst[e]] + rank[e];
        esrt[pos] = src[e];
    }
}

// ---------------- Layer-1 aggregate + fused ELU + layer-2 prep --------------
// 32 threads per node; plain (no-max) softmax; self-loop inline; unroll x4.
__global__ void k4_layer1(const int* __restrict__ rp, const int* __restrict__ esrt,
                          const __half* __restrict__ h1, const float* __restrict__ as1,
                          const float* __restrict__ ad1, const float* __restrict__ b1,
                          const float* __restrict__ W2, const float* __restrict__ a_src2,
                          const float* __restrict__ a_dst2,
                          float4* __restrict__ h2p, float* __restrict__ ad2,
                          int N) {
    int t = blockIdx.x * blockDim.x + threadIdx.x;
    int n = t >> 5;
    int c = t & 31;
    if (n >= N) return;
    int hh = c >> 4;
    const float2* as1v = reinterpret_cast<const float2*>(as1);
    const float2* ad1v = reinterpret_cast<const float2*>(ad1);
    float2 adv = ad1v[n];
    float ad = hh ? adv.y : adv.x;
    // self-loop contribution (coalesced own-row reads)
    float2 asv_self = as1v[n];
    float e_self = lrelu((hh ? asv_self.y : asv_self.x) + ad);
    float w_self = __expf(fminf(e_self, ECLAMP));
    float s0 = w_self, s1 = 0.f, s2 = 0.f, s3 = 0.f;
    float acc0 = w_self * __half2float(h1[n * 32 + c]);
    float acc1 = 0.f, acc2 = 0.f, acc3 = 0.f;

    int p0 = rp[n], p1 = rp[n + 1];
    int p = p0;
    for (; p + 3 < p1; p += 4) {              // 4 independent chains for MLP
        int sa = esrt[p];
        int sb = esrt[p + 1];
        int sc_ = esrt[p + 2];
        int sd = esrt[p + 3];
        float2 va = as1v[sa];
        float2 vb = as1v[sb];
        float2 vc = as1v[sc_];
        float2 vd = as1v[sd];
        float ha = __half2float(h1[(size_t)sa * 32 + c]);
        float hb = __half2float(h1[(size_t)sb * 32 + c]);
        float hc = __half2float(h1[(size_t)sc_ * 32 + c]);
        float hd = __half2float(h1[(size_t)sd * 32 + c]);
        float pa = __expf(fminf(lrelu((hh ? va.y : va.x) + ad), ECLAMP));
        float pb = __expf(fminf(lrelu((hh ? vb.y : vb.x) + ad), ECLAMP));
        float pc = __expf(fminf(lrelu((hh ? vc.y : vc.x) + ad), ECLAMP));
        float pd = __expf(fminf(lrelu((hh ? vd.y : vd.x) + ad), ECLAMP));
        s0 += pa;   acc0 += pa * ha;
        s1 += pb;   acc1 += pb * hb;
        s2 += pc;   acc2 += pc * hc;
        s3 += pd;   acc3 += pd * hd;
    }
    for (; p < p1; ++p) {
        int sa = esrt[p];
        float2 va = as1v[sa];
        float ha = __half2float(h1[(size_t)sa * 32 + c]);
        float pa = __expf(fminf(lrelu((hh ? va.y : va.x) + ad), ECLAMP));
        s0 += pa;   acc0 += pa * ha;
    }
    float s = (s0 + s1) + (s2 + s3);
    float acc = (acc0 + acc1) + (acc2 + acc3);
    float o = acc / s + b1[c];
    o = o > 0.f ? o : expm1f(o);                   // ELU
    // fused layer-2 prep: h2 = o @ W2  (reduce over all 32 channels)
    float t0 = o * W2[c * 2 + 0];
    float t1 = o * W2[c * 2 + 1];
#pragma unroll
    for (int msk = 16; msk >= 1; msk >>= 1) {
        t0 += __shfl_xor(t0, msk);
        t1 += __shfl_xor(t1, msk);
    }
    if (c == 0) {
        float as2v = t0 * a_src2[0] + t1 * a_src2[1];
        float ad2v = t0 * a_dst2[0] + t1 * a_dst2[1];
        h2p[n] = make_float4(t0, t1, as2v, 0.f);   // single 16B gather target
        ad2[n] = ad2v;
    }
}

// ---------------- Layer-2 aggregate → output --------------------------------
// 4 lanes per node; each lane strides edges by 4; shfl combine.
__global__ void k5_layer2(const int* __restrict__ rp, const int* __restrict__ esrt,
                          const float4* __restrict__ h2p, const float* __restrict__ ad2,
                          const float* __restrict__ b2,
                          float* __restrict__ out, int N) {
    int t = blockIdx.x * blockDim.x + threadIdx.x;
    int n = t >> 2;
    int sub = t & 3;
    if (n >= N) return;
    float ad = ad2[n];
    float s = 0.f, xx = 0.f, yy = 0.f;
    if (sub == 0) {                            // self-loop (coalesced own-row)
        float4 hv = h2p[n];
        float w = __expf(fminf(lrelu(hv.z + ad), ECLAMP));
        s = w; xx = w * hv.x; yy = w * hv.y;
    }
    int p0 = rp[n], p1 = rp[n + 1];
    for (int p = p0 + sub; p < p1; p += 4) {
        int sn = esrt[p];
        float4 hv = h2p[sn];                   // single 16B random gather
        float w = __expf(fminf(lrelu(hv.z + ad), ECLAMP));
        s += w; xx += w * hv.x; yy += w * hv.y;
    }
#pragma unroll
    for (int msk = 1; msk <= 2; msk <<= 1) {   // combine the 4-lane quad
        s  += __shfl_xor(s, msk);
        xx += __shfl_xor(xx, msk);
        yy += __shfl_xor(yy, msk);
    }
    if (sub == 0) {
        float2 o;
        o.x = xx / s + b2[0];
        o.y = yy / s + b2[1];
        reinterpret_cast<float2*>(out)[n] = o;
    }
}

extern "C" void kernel_launch(void* const* d_in, const int* in_sizes, int n_in,
                              void* d_out, int out_size, void* d_ws, size_t ws_size,
                              hipStream_t stream) {
    const float* x      = (const float*)d_in[0];
    const int*   ei     = (const int*)d_in[1];   // int32 (JAX x64 disabled)
    const float* W1     = (const float*)d_in[2];
    const float* a_src1 = (const float*)d_in[3];
    const float* a_dst1 = (const float*)d_in[4];
    const float* b1     = (const float*)d_in[5];
    const float* W2     = (const float*)d_in[6];
    const float* a_src2 = (const float*)d_in[7];
    const float* a_dst2 = (const float*)d_in[8];
    const float* b2     = (const float*)d_in[9];
    float* out = (float*)d_out;

    const int N = in_sizes[0] / 4;    // x is [N,4]
    const int E = in_sizes[1] / 2;    // edge_index is [2,E]
    const int* srcp = ei;
    const int* dstp = ei + E;
    const int nb = (N + SCAN_CHUNK - 1) / SCAN_CHUNK;

    // workspace layout (h2p first-aligned 16B; all chunks multiple of 16B)
    __half* h1   = (__half*)d_ws;                  // N*32 fp16 (6.4MB)
    float*  as1  = (float*)(h1 + (size_t)N * 32);  // N*2
    float*  ad1  = as1 + (size_t)N * 2;            // N*2
    float4* h2p  = (float4*)(ad1 + (size_t)N * 2); // N float4 (16B aligned)
    float*  ad2  = (float*)(h2p + (size_t)N);      // N
    int* deg   = (int*)(ad2 + (size_t)N);          // N
    int* rp    = deg  + (size_t)N;                 // N+1 (rounded to +4)
    int* rank  = rp   + (size_t)(N + 4);           // E
    int* bsum  = rank + (size_t)E;                 // nb
    int* bscan = bsum + (size_t)nb;                // nb
    int* esrt  = bscan + (size_t)nb;               // E

    const int BT = 256;
    k0_prep1<<<((size_t)N * 32 + BT - 1) / BT, BT, 0, stream>>>(
        x, W1, a_src1, a_dst1, h1, as1, ad1, N);
    k1a_init_deg<<<(N + BT - 1) / BT, BT, 0, stream>>>(deg, N);
    k1b_hist<<<(E + BT - 1) / BT, BT, 0, stream>>>(dstp, deg, rank, E);
    k2a_partials<<<nb, 256, 0, stream>>>(deg, bsum, N);
    k2b_scanb<<<1, 1024, 0, stream>>>(bsum, bscan, nb, rp, N);
    k2c_scan<<<nb, 256, 0, stream>>>(deg, bscan, rp, N);
    k3b_scatter<<<(E + BT - 1) / BT, BT, 0, stream>>>(srcp, dstp, rp, rank, esrt, E);
    k4_layer1<<<((size_t)N * 32 + BT - 1) / BT, BT, 0, stream>>>(
        rp, esrt, h1, as1, ad1, b1, W2, a_src2, a_dst2, h2p, ad2, N);
    k5_layer2<<<((size_t)N * 4 + BT - 1) / BT, BT, 0, stream>>>(
        rp, esrt, h2p, ad2, b2, out, N);
}

// Round 5
// 211.290 us; speedup vs baseline: 2.3002x; 1.2267x over previous
//
#include <hip/hip_runtime.h>
#include <hip/hip_fp16.h>
#include <math.h>

#define NEG_SLOPE 0.2f
#define SCAN_CHUNK 2048     // per-block elements in hierarchical scan (256 thr * 8)
#define ECLAMP 80.0f        // exp() inf-safety clamp (never hit statistically)
#define BUCKET_SHIFT 8      // 256 nodes per bucket
#define BUCKET_MASK 255
#define EB_CHUNK 8192       // edges per partition block (256 thr * 32)

__device__ __forceinline__ float lrelu(float e) {
    return e > 0.f ? e : NEG_SLOPE * e;
}

// ---------------- Layer-1 node prep: h1[N,32] (fp16), as1[N,2], ad1[N,2] ----
// 32 threads per node; lane c owns channel c (head = c>>4).
__global__ void k0_prep1(const float* __restrict__ x,
                         const float* __restrict__ W1,
                         const float* __restrict__ a_src1,
                         const float* __restrict__ a_dst1,
                         __half* __restrict__ h1,
                         float* __restrict__ as1,
                         float* __restrict__ ad1,
                         int N) {
    int t = blockIdx.x * blockDim.x + threadIdx.x;
    int n = t >> 5;
    int c = t & 31;
    if (n >= N) return;
    const float4 xv = reinterpret_cast<const float4*>(x)[n];  // broadcast within group
    float h = xv.x * W1[c] + xv.y * W1[32 + c] + xv.z * W1[64 + c] + xv.w * W1[96 + c];
    h1[n * 32 + c] = __float2half(h);         // coalesced 64B per group
    float ts = h * a_src1[c];                 // a_src1 flat [h*16+cc] == [c]
    float td = h * a_dst1[c];
#pragma unroll
    for (int m = 8; m >= 1; m >>= 1) {        // reduce over 16 channels of this head
        ts += __shfl_xor(ts, m);
        td += __shfl_xor(td, m);
    }
    if ((c & 15) == 0) {
        int hh = c >> 4;
        as1[n * 2 + hh] = ts;
        ad1[n * 2 + hh] = td;
    }
}

// ---------------- CSR build: two-level counting sort (no global atomics) ----
// P1: per-edge-block LDS histogram over dst-buckets -> cmatT[b][blk]
__global__ void p1_hist(const int* __restrict__ dst, int* __restrict__ cmatT,
                        int E, int NB, int nblkE) {
    __shared__ int cnt[512];
    const int blk = blockIdx.x, tid = threadIdx.x;
    for (int b = tid; b < NB; b += 256) cnt[b] = 0;
    __syncthreads();
    int base = blk * EB_CHUNK;
    int end = min(base + EB_CHUNK, E);
    for (int e = base + tid; e < end; e += 256)
        atomicAdd(&cnt[dst[e] >> BUCKET_SHIFT], 1);
    __syncthreads();
    for (int b = tid; b < NB; b += 256)
        cmatT[(size_t)b * nblkE + blk] = cnt[b];
}

// --------- hierarchical exclusive scan (generic, over n ints) ---------------
__global__ void k2a_partials(const int* __restrict__ in, int* __restrict__ bsum, int n) {
    __shared__ int ws[4];
    const int tid = threadIdx.x;              // 256
    const int lane = tid & 63, wid = tid >> 6;
    int base = blockIdx.x * SCAN_CHUNK + tid * 8;
    int lsum = 0;
#pragma unroll
    for (int i = 0; i < 8; ++i) {
        int idx = base + i;
        lsum += (idx < n) ? in[idx] : 0;
    }
#pragma unroll
    for (int m = 32; m >= 1; m >>= 1) lsum += __shfl_xor(lsum, m);
    if (lane == 0) ws[wid] = lsum;
    __syncthreads();
    if (tid == 0) bsum[blockIdx.x] = ws[0] + ws[1] + ws[2] + ws[3];
}

__global__ void k2b_scanb(const int* __restrict__ bsum, int* __restrict__ bscan, int nb) {
    __shared__ int wsum[16];
    const int tid = threadIdx.x;              // 1024
    const int lane = tid & 63, wid = tid >> 6;
    int carry = 0;
    for (int base = 0; base < nb; base += 1024) {
        int i = base + tid;
        int v = (i < nb) ? bsum[i] : 0;
        int xx = v;
#pragma unroll
        for (int off = 1; off < 64; off <<= 1) {
            int t = __shfl_up(xx, off);
            if (lane >= off) xx += t;
        }
        if (lane == 63) wsum[wid] = xx;
        __syncthreads();
        int woff = 0;
        for (int w = 0; w < wid; ++w) woff += wsum[w];
        if (i < nb) bscan[i] = carry + woff + xx - v;
        int tot = 0;
        for (int w = 0; w < 16; ++w) tot += wsum[w];
        carry += tot;
        __syncthreads();
    }
}

__global__ void k2c_scan(const int* __restrict__ in, const int* __restrict__ bscan,
                         int* __restrict__ out, int n) {
    __shared__ int ws[4];
    const int tid = threadIdx.x;              // 256
    const int lane = tid & 63, wid = tid >> 6;
    int base = blockIdx.x * SCAN_CHUNK + tid * 8;
    int v[8], pre[8];
    int lsum = 0;
#pragma unroll
    for (int i = 0; i < 8; ++i) {
        int idx = base + i;
        v[i] = (idx < n) ? in[idx] : 0;
        pre[i] = lsum;
        lsum += v[i];
    }
    int xs = lsum;
#pragma unroll
    for (int off = 1; off < 64; off <<= 1) {
        int t = __shfl_up(xs, off);
        if (lane >= off) xs += t;
    }
    if (lane == 63) ws[wid] = xs;
    __syncthreads();
    int woff = 0;
    for (int w = 0; w < wid; ++w) woff += ws[w];
    int off0 = bscan[blockIdx.x] + woff + xs - lsum;
#pragma unroll
    for (int i = 0; i < 8; ++i) {
        int idx = base + i;
        if (idx < n) out[idx] = off0 + pre[i];
    }
}

// P3: scatter edges into bucket-partitioned ebuf via LDS cursors
__global__ void p3_scatter(const int* __restrict__ src, const int* __restrict__ dst,
                           const int* __restrict__ cscan, unsigned int* __restrict__ ebuf,
                           int E, int NB, int nblkE) {
    __shared__ int cur[512];
    const int blk = blockIdx.x, tid = threadIdx.x;
    for (int b = tid; b < NB; b += 256)
        cur[b] = cscan[(size_t)b * nblkE + blk];
    __syncthreads();
    int base = blk * EB_CHUNK;
    int end = min(base + EB_CHUNK, E);
    for (int e = base + tid; e < end; e += 256) {
        int d = dst[e];
        int b = d >> BUCKET_SHIFT;
        int pos = atomicAdd(&cur[b], 1);
        ebuf[pos] = (unsigned int)src[e] | ((unsigned int)(d & BUCKET_MASK) << 24);
    }
}

// P4: per-bucket CSR finalize: local hist -> local scan -> rp + esrt
__global__ void p4_csr(const unsigned int* __restrict__ ebuf,
                       const int* __restrict__ cscan,
                       int* __restrict__ rp, int* __restrict__ esrt,
                       int N, int E, int NB, int nblkE) {
    __shared__ int degl[256];
    __shared__ int curl[256];
    __shared__ int wsum[4];
    const int b = blockIdx.x, tid = threadIdx.x;
    const int lane = tid & 63, wid = tid >> 6;
    int bstart = cscan[(size_t)b * nblkE];
    int bend = (b + 1 < NB) ? cscan[(size_t)(b + 1) * nblkE] : E;
    degl[tid] = 0;
    __syncthreads();
    for (int i = bstart + tid; i < bend; i += 256)
        atomicAdd(&degl[ebuf[i] >> 24], 1);
    __syncthreads();
    int v = degl[tid];
    int xs = v;
#pragma unroll
    for (int off = 1; off < 64; off <<= 1) {
        int t = __shfl_up(xs, off);
        if (lane >= off) xs += t;
    }
    if (lane == 63) wsum[wid] = xs;
    __syncthreads();
    int woff = 0;
    for (int w = 0; w < wid; ++w) woff += wsum[w];
    int excl = woff + xs - v;                 // exclusive prefix within bucket
    int node = (b << BUCKET_SHIFT) + tid;
    if (node < N) rp[node] = bstart + excl;
    curl[tid] = bstart + excl;
    if (b == 0 && tid == 0) rp[N] = E;
    __syncthreads();
    for (int i = bstart + tid; i < bend; i += 256) {
        unsigned int ev = ebuf[i];
        int dl = ev >> 24;
        int pos = atomicAdd(&curl[dl], 1);
        esrt[pos] = (int)(ev & 0x00FFFFFFu);
    }
}

// ---------------- Layer-1 aggregate + fused ELU + layer-2 prep --------------
// 32 threads per node; plain (no-max) softmax; self-loop inline; unroll x4.
__global__ void k4_layer1(const int* __restrict__ rp, const int* __restrict__ esrt,
                          const __half* __restrict__ h1, const float* __restrict__ as1,
                          const float* __restrict__ ad1, const float* __restrict__ b1,
                          const float* __restrict__ W2, const float* __restrict__ a_src2,
                          const float* __restrict__ a_dst2,
                          float4* __restrict__ h2p, float* __restrict__ ad2,
                          int N) {
    int t = blockIdx.x * blockDim.x + threadIdx.x;
    int n = t >> 5;
    int c = t & 31;
    if (n >= N) return;
    int hh = c >> 4;
    const float2* as1v = reinterpret_cast<const float2*>(as1);
    const float2* ad1v = reinterpret_cast<const float2*>(ad1);
    float2 adv = ad1v[n];
    float ad = hh ? adv.y : adv.x;
    // self-loop contribution (coalesced own-row reads)
    float2 asv_self = as1v[n];
    float e_self = lrelu((hh ? asv_self.y : asv_self.x) + ad);
    float w_self = __expf(fminf(e_self, ECLAMP));
    float s0 = w_self, s1 = 0.f, s2 = 0.f, s3 = 0.f;
    float acc0 = w_self * __half2float(h1[n * 32 + c]);
    float acc1 = 0.f, acc2 = 0.f, acc3 = 0.f;

    int p0 = rp[n], p1 = rp[n + 1];
    int p = p0;
    for (; p + 3 < p1; p += 4) {              // 4 independent chains for MLP
        int sa = esrt[p];
        int sb = esrt[p + 1];
        int sc_ = esrt[p + 2];
        int sd = esrt[p + 3];
        float2 va = as1v[sa];
        float2 vb = as1v[sb];
        float2 vc = as1v[sc_];
        float2 vd = as1v[sd];
        float ha = __half2float(h1[(size_t)sa * 32 + c]);
        float hb = __half2float(h1[(size_t)sb * 32 + c]);
        float hc = __half2float(h1[(size_t)sc_ * 32 + c]);
        float hd = __half2float(h1[(size_t)sd * 32 + c]);
        float pa = __expf(fminf(lrelu((hh ? va.y : va.x) + ad), ECLAMP));
        float pb = __expf(fminf(lrelu((hh ? vb.y : vb.x) + ad), ECLAMP));
        float pc = __expf(fminf(lrelu((hh ? vc.y : vc.x) + ad), ECLAMP));
        float pd = __expf(fminf(lrelu((hh ? vd.y : vd.x) + ad), ECLAMP));
        s0 += pa;   acc0 += pa * ha;
        s1 += pb;   acc1 += pb * hb;
        s2 += pc;   acc2 += pc * hc;
        s3 += pd;   acc3 += pd * hd;
    }
    for (; p < p1; ++p) {
        int sa = esrt[p];
        float2 va = as1v[sa];
        float ha = __half2float(h1[(size_t)sa * 32 + c]);
        float pa = __expf(fminf(lrelu((hh ? va.y : va.x) + ad), ECLAMP));
        s0 += pa;   acc0 += pa * ha;
    }
    float s = (s0 + s1) + (s2 + s3);
    float acc = (acc0 + acc1) + (acc2 + acc3);
    float o = acc / s + b1[c];
    o = o > 0.f ? o : expm1f(o);                   // ELU
    // fused layer-2 prep: h2 = o @ W2  (reduce over all 32 channels)
    float t0 = o * W2[c * 2 + 0];
    float t1 = o * W2[c * 2 + 1];
#pragma unroll
    for (int msk = 16; msk >= 1; msk >>= 1) {
        t0 += __shfl_xor(t0, msk);
        t1 += __shfl_xor(t1, msk);
    }
    if (c == 0) {
        float as2v = t0 * a_src2[0] + t1 * a_src2[1];
        float ad2v = t0 * a_dst2[0] + t1 * a_dst2[1];
        h2p[n] = make_float4(t0, t1, as2v, 0.f);   // single 16B gather target
        ad2[n] = ad2v;
    }
}

// ---------------- Layer-2 aggregate → output --------------------------------
// 4 lanes per node; each lane strides edges by 4; shfl combine.
__global__ void k5_layer2(const int* __restrict__ rp, const int* __restrict__ esrt,
                          const float4* __restrict__ h2p, const float* __restrict__ ad2,
                          const float* __restrict__ b2,
                          float* __restrict__ out, int N) {
    int t = blockIdx.x * blockDim.x + threadIdx.x;
    int n = t >> 2;
    int sub = t & 3;
    if (n >= N) return;
    float ad = ad2[n];
    float s = 0.f, xx = 0.f, yy = 0.f;
    if (sub == 0) {                            // self-loop (coalesced own-row)
        float4 hv = h2p[n];
        float w = __expf(fminf(lrelu(hv.z + ad), ECLAMP));
        s = w; xx = w * hv.x; yy = w * hv.y;
    }
    int p0 = rp[n], p1 = rp[n + 1];
    for (int p = p0 + sub; p < p1; p += 4) {
        int sn = esrt[p];
        float4 hv = h2p[sn];                   // single 16B random gather
        float w = __expf(fminf(lrelu(hv.z + ad), ECLAMP));
        s += w; xx += w * hv.x; yy += w * hv.y;
    }
#pragma unroll
    for (int msk = 1; msk <= 2; msk <<= 1) {   // combine the 4-lane quad
        s  += __shfl_xor(s, msk);
        xx += __shfl_xor(xx, msk);
        yy += __shfl_xor(yy, msk);
    }
    if (sub == 0) {
        float2 o;
        o.x = xx / s + b2[0];
        o.y = yy / s + b2[1];
        reinterpret_cast<float2*>(out)[n] = o;
    }
}

extern "C" void kernel_launch(void* const* d_in, const int* in_sizes, int n_in,
                              void* d_out, int out_size, void* d_ws, size_t ws_size,
                              hipStream_t stream) {
    const float* x      = (const float*)d_in[0];
    const int*   ei     = (const int*)d_in[1];   // int32 (JAX x64 disabled)
    const float* W1     = (const float*)d_in[2];
    const float* a_src1 = (const float*)d_in[3];
    const float* a_dst1 = (const float*)d_in[4];
    const float* b1     = (const float*)d_in[5];
    const float* W2     = (const float*)d_in[6];
    const float* a_src2 = (const float*)d_in[7];
    const float* a_dst2 = (const float*)d_in[8];
    const float* b2     = (const float*)d_in[9];
    float* out = (float*)d_out;

    const int N = in_sizes[0] / 4;    // x is [N,4]
    const int E = in_sizes[1] / 2;    // edge_index is [2,E]
    const int* srcp = ei;
    const int* dstp = ei + E;

    const int NB    = (N + BUCKET_MASK) >> BUCKET_SHIFT;   // dst buckets (<=512)
    const int nblkE = (E + EB_CHUNK - 1) / EB_CHUNK;       // edge partition blocks
    const int M     = NB * nblkE;                          // count-matrix size
    const int nb2   = (M + SCAN_CHUNK - 1) / SCAN_CHUNK;   // scan blocks over M

    // workspace layout
    char* w = (char*)d_ws;
    __half* h1   = (__half*)w;  w += (size_t)N * 32 * sizeof(__half);
    float*  as1  = (float*)w;   w += (size_t)N * 2 * sizeof(float);
    float*  ad1  = (float*)w;   w += (size_t)N * 2 * sizeof(float);
    float4* h2p  = (float4*)w;  w += (size_t)N * sizeof(float4);   // offset 8MB: 16B aligned
    float*  ad2  = (float*)w;   w += (size_t)N * sizeof(float);
    int* rp     = (int*)w;      w += (size_t)(N + 4) * sizeof(int);
    int* cmatT  = (int*)w;      w += (size_t)M * sizeof(int);
    int* cscan  = (int*)w;      w += (size_t)M * sizeof(int);
    int* bsum   = (int*)w;      w += (size_t)(nb2 + 4) * sizeof(int);
    int* bscan  = (int*)w;      w += (size_t)(nb2 + 4) * sizeof(int);
    unsigned int* ebuf = (unsigned int*)w;  w += (size_t)E * sizeof(unsigned int);
    int* esrt   = (int*)w;      w += (size_t)E * sizeof(int);

    const int BT = 256;
    k0_prep1<<<((size_t)N * 32 + BT - 1) / BT, BT, 0, stream>>>(
        x, W1, a_src1, a_dst1, h1, as1, ad1, N);
    p1_hist<<<nblkE, 256, 0, stream>>>(dstp, cmatT, E, NB, nblkE);
    k2a_partials<<<nb2, 256, 0, stream>>>(cmatT, bsum, M);
    k2b_scanb<<<1, 1024, 0, stream>>>(bsum, bscan, nb2);
    k2c_scan<<<nb2, 256, 0, stream>>>(cmatT, bscan, cscan, M);
    p3_scatter<<<nblkE, 256, 0, stream>>>(srcp, dstp, cscan, ebuf, E, NB, nblkE);
    p4_csr<<<NB, 256, 0, stream>>>(ebuf, cscan, rp, esrt, N, E, NB, nblkE);
    k4_layer1<<<((size_t)N * 32 + BT - 1) / BT, BT, 0, stream>>>(
        rp, esrt, h1, as1, ad1, b1, W2, a_src2, a_dst2, h2p, ad2, N);
    k5_layer2<<<((size_t)N * 4 + BT - 1) / BT, BT, 0, stream>>>(
        rp, esrt, h2p, ad2, b2, out, N);
}